// Round 17
// baseline (489.437 us; speedup 1.0000x reference)
//
#include <hip/hip_runtime.h>
#include <stdint.h>

#define M_DIM 8192
#define K_DIM 4096
#define N_DIM 4096
#define KTILES (K_DIM / 64)

typedef __attribute__((ext_vector_type(4))) int i32x4;

// ---------------------------------------------------------------------------
// Pack int32-stored int8 weights [N,K] -> true int8 [N,K]; per-row sum folded
// into integer correction corr[n] = (128 - zp) * rowsum[n].
// ---------------------------------------------------------------------------
__global__ void pack_w_kernel(const int* __restrict__ w, char* __restrict__ wp,
                              int* __restrict__ corr, const int* __restrict__ zpp) {
  __shared__ int red[256];
  const int n = blockIdx.x;
  const int t = threadIdx.x;
  const int4* row = (const int4*)(w + (size_t)n * K_DIM);
  int s = 0;
  int words[4];
#pragma unroll
  for (int u = 0; u < 4; ++u) {
    int4 v = row[t * 4 + u];
    s += v.x + v.y + v.z + v.w;
    words[u] = (v.x & 255) | ((v.y & 255) << 8) | ((v.z & 255) << 16) | (v.w << 24);
  }
  ((int4*)(wp + (size_t)n * K_DIM))[t] = make_int4(words[0], words[1], words[2], words[3]);
  red[t] = s;
  __syncthreads();
  for (int off = 128; off > 0; off >>= 1) {
    if (t < off) red[t] += red[t + off];
    __syncthreads();
  }
  if (t == 0) corr[n] = (128 - zpp[0]) * red[0];
}

// ---------------------------------------------------------------------------
// Quantize fp32 input -> int8 (q - 128), 4 elements/thread.
// ---------------------------------------------------------------------------
__global__ void quant_in_kernel(const float* __restrict__ x, char* __restrict__ q,
                                const float* __restrict__ sp, const int* __restrict__ zpp) {
  const int i = blockIdx.x * blockDim.x + threadIdx.x;
  const float s = sp[0];
  const float zp = (float)zpp[0];
  float4 v = ((const float4*)x)[i];
  float t0 = fminf(fmaxf(rintf(v.x / s) + zp, 0.f), 255.f);
  float t1 = fminf(fmaxf(rintf(v.y / s) + zp, 0.f), 255.f);
  float t2 = fminf(fmaxf(rintf(v.z / s) + zp, 0.f), 255.f);
  float t3 = fminf(fmaxf(rintf(v.w / s) + zp, 0.f), 255.f);
  int b0 = (int)t0 - 128, b1 = (int)t1 - 128, b2 = (int)t2 - 128, b3 = (int)t3 - 128;
  ((int*)q)[i] = (b0 & 255) | ((b1 & 255) << 8) | ((b2 & 255) << 16) | (b3 << 24);
}

// ---------------------------------------------------------------------------
// 256x128 i8 GEMM blocks, TWO independent blocks per CU.
// R17 = R16 with the one bug fixed: TILE3 read B via cA_+16384 while boff[]
// ALSO carried the +16384 B-region base -> B frags read from slot_base+32768
// (past the 24576B slot, i.e. the next slot's A data) -> absmax 15314.
// Now both A and B read from the slot base; aoff/boff carry region offsets.
// Per block: 512 thr = 8 waves (4M x 2N), 64x64 out/wave, acc 4x4 = 64 AGPR
// + 64 arch = 128/wave; 2 blocks x 2 waves/SIMD x 128 = the 512-reg pool.
// Two async barrier domains/CU: block A's MFMA bursts cover block B's
// read/stage/barrier stalls (m114 mechanism).
// LDS: ring-3 x (A 16KB + B 8KB) = 72KB/block; 2 blocks = 144KB <= 160.
// Ledger (3 stages/tile, dist 2): stage during t -> slot (t+2)%3 ==
// (t-1)%3 (reads finished before t-1's end barrier); end-of-t vmcnt(3)
// retires t-1's stages -> slot t+1 confirmed. Prologue stages slots 0,1,
// vmcnt(3) confirms slot 0. Tail: clamped dead re-stages.
// Swizzle (0-conflict R1-R15): phys 16B slot = g ^ ((row>>1)&3) on staging
// source and ds_read addr. B content permutation (R8/R9-validated): LDS row
// rho holds weight row (rho&~63)+4*(rho&15)+((rho>>4)&3) -> epilogue n =
// base+4c+j consecutive -> packed full-line stores (WRITE_SIZE = 32MB).
// ---------------------------------------------------------------------------
#define STAGE16(SRC, DST)                                                     \
  __builtin_amdgcn_global_load_lds(                                           \
      (const __attribute__((address_space(1))) void*)(SRC),                   \
      (__attribute__((address_space(3))) void*)(DST), 16, 0, 0)

#define RD(p) (*(const i32x4*)(p))

#define TILE3(SLOT, KS)                                                       \
  {                                                                           \
    const char* c_ = lds + (SLOT) * 24576;                                    \
    char* nx_ = lds + (((SLOT) + 2) % 3) * 24576;                             \
    i32x4 a_[4], b_[4];                                                       \
    _Pragma("unroll") for (int i_ = 0; i_ < 4; ++i_)                          \
        a_[i_] = RD(c_ + aoff[i_]);                                           \
    _Pragma("unroll") for (int j_ = 0; j_ < 4; ++j_)                          \
        b_[j_] = RD(c_ + boff[j_]);                                           \
    STAGE16(asr0 + (size_t)(KS), nx_ + oa0);                                  \
    STAGE16(asr1 + (size_t)(KS), nx_ + oa1);                                  \
    STAGE16(bsr0 + (size_t)(KS), nx_ + ob0);                                  \
    __builtin_amdgcn_s_setprio(1);                                            \
    _Pragma("unroll") for (int i_ = 0; i_ < 4; ++i_)                          \
        _Pragma("unroll") for (int j_ = 0; j_ < 4; ++j_)                      \
            acc[i_][j_] = __builtin_amdgcn_mfma_i32_16x16x64_i8(              \
                a_[i_], b_[j_], acc[i_][j_], 0, 0, 0);                        \
    __builtin_amdgcn_s_setprio(0);                                            \
    asm volatile("s_waitcnt vmcnt(3)" ::: "memory");                          \
    __builtin_amdgcn_s_barrier();                                             \
  }

template <int WRITE_Q>
__global__ __launch_bounds__(512, 4) void gemm_kernel(
    const char* __restrict__ qa, const char* __restrict__ wb,
    const int* __restrict__ corr, const float* __restrict__ swp,
    const float* __restrict__ bias, const float* __restrict__ sp,
    const int* __restrict__ zpp, char* __restrict__ outq, float* __restrict__ outf) {
  __shared__ __align__(16) char lds[3 * 24576];  // 72 KB: ring-3, A@0 B@16K
  const int tid = threadIdx.x;
  const int lane = tid & 63;
  const int w = tid >> 6;   // 8 waves
  const int wr = w >> 1;    // 0..3 (M, 64 each)
  const int wc = w & 1;     // 0..1 (N, 64 each)
  const int bid = blockIdx.x;
  const int bm = bid & 31;  // M/256 = 32, fastest: neighbors share B panel
  const int bn = bid >> 5;  // N/128 = 32
  const char* abase = qa + (size_t)bm * 256 * K_DIM;
  const char* bbase = wb + (size_t)bn * 128 * K_DIM;

  // --- staging constants: A 16KB = 2 chunks, B 8KB = 1 chunk (512thr x 16B)
  const int oa0 = tid * 16;
  const int oa1 = 8192 + tid * 16;
  const int ob0 = 16384 + tid * 16;
  const int sl_ = tid & 3;
  const int ra0 = (tid * 16) >> 6;           // A rows 0..127
  const int ra1 = (8192 + tid * 16) >> 6;    // A rows 128..255
  const int rb0 = (tid * 16) >> 6;           // B rows 0..127
  const char* asr0 = abase + (size_t)ra0 * K_DIM + (sl_ ^ ((ra0 >> 1) & 3)) * 16;
  const char* asr1 = abase + (size_t)ra1 * K_DIM + (sl_ ^ ((ra1 >> 1) & 3)) * 16;
  // B content permutation: LDS row rho holds weight row (rho&~63)+4*(rho&15)+((rho>>4)&3)
  const int pb0 = (rb0 & ~63) + 4 * (rb0 & 15) + ((rb0 >> 4) & 3);
  const char* bsr0 = bbase + (size_t)pb0 * K_DIM + (sl_ ^ ((rb0 >> 1) & 3)) * 16;

  // --- per-lane ds_read byte offsets (swizzled; boff carries B base) ---
  const int rr = lane & 15;
  const int g = lane >> 4;
  int aoff[4], boff[4];
#pragma unroll
  for (int i = 0; i < 4; ++i) {
    const int rowA = wr * 64 + i * 16 + rr;
    aoff[i] = (rowA << 6) + ((g ^ ((rowA >> 1) & 3)) << 4);
    const int rowB = wc * 64 + i * 16 + rr;
    boff[i] = 16384 + (rowB << 6) + ((g ^ ((rowB >> 1) & 3)) << 4);
  }

  i32x4 acc[4][4] = {};

  // --- prologue: stage slots 0,1 (tiles 0,1); vmcnt(3) confirms slot 0 ---
  STAGE16(asr0, lds + oa0); STAGE16(asr1, lds + oa1); STAGE16(bsr0, lds + ob0);
  STAGE16(asr0 + 64, lds + 24576 + oa0);
  STAGE16(asr1 + 64, lds + 24576 + oa1);
  STAGE16(bsr0 + 64, lds + 24576 + ob0);
  asm volatile("s_waitcnt vmcnt(3)" ::: "memory");
  __builtin_amdgcn_s_barrier();

  // --- main loop: 64 tiles = 21 x 3 + 1; clamped tail re-stages (dead) ---
#define KCL(x) ((size_t)((x) < KTILES ? (x) : KTILES - 1) * 64)
  for (int t3 = 0; t3 < 21; ++t3) {
    const int t0 = t3 * 3;
    TILE3(0, KCL(t0 + 2))
    TILE3(1, KCL(t0 + 3))
    TILE3(2, KCL(t0 + 4))
  }
  TILE3(0, KCL(KTILES - 1))  // t = 63 (slot 0), dead stage into slot 2
#undef KCL
  asm volatile("s_waitcnt vmcnt(0)" ::: "memory");  // drain before exit

  // --- epilogue (R9-validated): frag j, lane c -> n = nb4 + j ---
  const float s = sp[0];
  const float zpf = (float)zpp[0];
  const int m0 = bm * 256 + wr * 64 + (lane >> 4) * 4;
  const int nb4 = bn * 128 + wc * 64 + ((lane & 15) << 2);
  const int4 cr4 = *(const int4*)(corr + nb4);
  const float4 sw4 = *(const float4*)(swp + nb4);
  const float4 bb4 = *(const float4*)(bias + nb4);
  const float fs0 = s * sw4.x, fs1 = s * sw4.y, fs2 = s * sw4.z, fs3 = s * sw4.w;
#pragma unroll
  for (int i = 0; i < 4; ++i) {
#pragma unroll
    for (int q = 0; q < 4; ++q) {
      const int m = m0 + i * 16 + q;
      const float v0 = fs0 * (float)(acc[i][0][q] + cr4.x) + bb4.x;
      const float v1 = fs1 * (float)(acc[i][1][q] + cr4.y) + bb4.y;
      const float v2 = fs2 * (float)(acc[i][2][q] + cr4.z) + bb4.z;
      const float v3 = fs3 * (float)(acc[i][3][q] + cr4.w) + bb4.w;
      if (WRITE_Q) {
        const int b0i = (int)fminf(fmaxf(rintf(v0 / s) + zpf, 0.f), 255.f) - 128;
        const int b1i = (int)fminf(fmaxf(rintf(v1 / s) + zpf, 0.f), 255.f) - 128;
        const int b2i = (int)fminf(fmaxf(rintf(v2 / s) + zpf, 0.f), 255.f) - 128;
        const int b3i = (int)fminf(fmaxf(rintf(v3 / s) + zpf, 0.f), 255.f) - 128;
        const uint32_t pk = (uint32_t)(b0i & 255) | ((uint32_t)(b1i & 255) << 8) |
                            ((uint32_t)(b2i & 255) << 16) | ((uint32_t)b3i << 24);
        *(uint32_t*)(outq + (size_t)m * N_DIM + nb4) = pk;
      } else {
        float4 o4;
        o4.x = v0; o4.y = v1; o4.z = v2; o4.w = v3;
        *(float4*)(outf + (size_t)m * N_DIM + nb4) = o4;
      }
    }
  }
}

// ---------------------------------------------------------------------------
extern "C" void kernel_launch(void* const* d_in, const int* in_sizes, int n_in,
                              void* d_out, int out_size, void* d_ws, size_t ws_size,
                              hipStream_t stream) {
  const float* x = (const float*)d_in[0];
  const int* wq = (const int*)d_in[1];
  const float* bias = (const float*)d_in[2];
  const float* s_in = (const float*)d_in[3];
  const int* zp_in = (const int*)d_in[4];
  const float* s_w = (const float*)d_in[5];
  float* out = (float*)d_out;

  const size_t WP_BYTES = (size_t)N_DIM * K_DIM;  // 16 MB packed int8 W
  const size_t Q_BYTES = (size_t)M_DIM * K_DIM;   // 32 MB int8 activations
  char* ws = (char*)d_ws;
  char* wp = ws;
  char* q1 = ws + WP_BYTES;
  char* q2 = q1 + Q_BYTES;
  int* corr = (int*)(q2 + Q_BYTES);
  const size_t NEEDED = WP_BYTES + 2 * Q_BYTES + (size_t)N_DIM * sizeof(int);
  if (ws_size < NEEDED) return;

  pack_w_kernel<<<N_DIM, 256, 0, stream>>>(wq, wp, corr, zp_in);
  quant_in_kernel<<<(M_DIM * K_DIM / 4) / 256, 256, 0, stream>>>(x, q1, s_in, zp_in);

  dim3 grid((M_DIM / 256) * (N_DIM / 128));  // 1024 blocks, 2 per CU
  dim3 blk(512);
  gemm_kernel<1><<<grid, blk, 0, stream>>>(q1, wp, corr, s_w, bias, s_in, zp_in, q2, nullptr);
  gemm_kernel<1><<<grid, blk, 0, stream>>>(q2, wp, corr, s_w, bias, s_in, zp_in, q1, nullptr);
  gemm_kernel<0><<<grid, blk, 0, stream>>>(q1, wp, corr, s_w, bias, s_in, zp_in, nullptr, out);
}

// Round 18
// 450.470 us; speedup vs baseline: 1.0865x; 1.0865x over previous
//
#include <hip/hip_runtime.h>
#include <stdint.h>

#define M_DIM 8192
#define K_DIM 4096
#define N_DIM 4096
#define KTILES (K_DIM / 64)

typedef __attribute__((ext_vector_type(4))) int i32x4;

// ---------------------------------------------------------------------------
// Pack int32-stored int8 weights [N,K] -> MFMA-fragment-major int8 layout:
//   frag F = (n&~63)/16 + (n&3), row r = (n&63)>>2   [n = b + 4r + j trick:
//   baked-in B permutation so epilogue n = base+4c+j is consecutive]
//   packed[((F*64 + kt)*1024) + (g*16 + r)*16 + byte] = W[n][kt*64+g*16+byte]
// A wave's B-fragment (16 n-rows x 16 k-bytes, lane=g*16+r) is then ONE
// coalesced 1KB region -> direct global_load_dwordx4, no LDS for B.
// Also per-row sum -> corr[n] = (128 - zp) * rowsum[n].
// ---------------------------------------------------------------------------
__global__ void pack_w_kernel(const int* __restrict__ w, char* __restrict__ wp,
                              int* __restrict__ corr, const int* __restrict__ zpp) {
  __shared__ int red[256];
  const int n = blockIdx.x;
  const int t = threadIdx.x;     // t -> (kt = t>>2, g = t&3)
  const int kt = t >> 2;
  const int g = t & 3;
  const int* row = w + (size_t)n * K_DIM + kt * 64 + g * 16;
  int s = 0;
  int words[4];
#pragma unroll
  for (int u = 0; u < 4; ++u) {
    int4 v = *(const int4*)(row + u * 4);
    s += v.x + v.y + v.z + v.w;
    words[u] = (v.x & 255) | ((v.y & 255) << 8) | ((v.z & 255) << 16) | (v.w << 24);
  }
  const int b = n & ~63;
  const int idx = n & 63;
  const int j = idx & 3;
  const int r = idx >> 2;
  const int F = (b >> 4) + j;
  char* dst = wp + ((size_t)F * 64 + kt) * 1024 + (g * 16 + r) * 16;
  *(int4*)dst = make_int4(words[0], words[1], words[2], words[3]);
  red[t] = s;
  __syncthreads();
  for (int off = 128; off > 0; off >>= 1) {
    if (t < off) red[t] += red[t + off];
    __syncthreads();
  }
  if (t == 0) corr[n] = (128 - zpp[0]) * red[0];
}

// ---------------------------------------------------------------------------
// Quantize fp32 input -> int8 (q - 128), 4 elements/thread.
// ---------------------------------------------------------------------------
__global__ void quant_in_kernel(const float* __restrict__ x, char* __restrict__ q,
                                const float* __restrict__ sp, const int* __restrict__ zpp) {
  const int i = blockIdx.x * blockDim.x + threadIdx.x;
  const float s = sp[0];
  const float zp = (float)zpp[0];
  float4 v = ((const float4*)x)[i];
  float t0 = fminf(fmaxf(rintf(v.x / s) + zp, 0.f), 255.f);
  float t1 = fminf(fmaxf(rintf(v.y / s) + zp, 0.f), 255.f);
  float t2 = fminf(fmaxf(rintf(v.z / s) + zp, 0.f), 255.f);
  float t3 = fminf(fmaxf(rintf(v.w / s) + zp, 0.f), 255.f);
  int b0 = (int)t0 - 128, b1 = (int)t1 - 128, b2 = (int)t2 - 128, b3 = (int)t3 - 128;
  ((int*)q)[i] = (b0 & 255) | ((b1 & 255) << 8) | ((b2 & 255) << 16) | (b3 << 24);
}

// ---------------------------------------------------------------------------
// 256x256 i8 GEMM = R14's 8-wave schedule with B taken DIRECT from packed
// global weights (no B LDS at all). Rationale: the R3-R15 floor is the LDS
// term (~1236 cyc/tile >= MFMA 1306); removing B cuts LDS to A-only
// (64KB reads + 16KB stage-writes ~ 940 cyc < MFMA). B-frag load = ONE
// coalesced 1KB global_load_dwordx4 from the L2-resident 1MB packed panel,
// prefetched 1 tile ahead in registers (replaces R14's tb_ ping set ->
// register-neutral, VGPR ~128, 2 waves/SIMD holds).
// Geometry: 512 thr = 8 waves (2M x 4N), per-wave 128x64, BK=64 B,
// mfma_i32_16x16x64_i8, 32 MFMA/wave/tile in two 16-clusters (shared b0).
// A: ring-4 x 16KB = 64KB LDS, prefetch dist 3, 2 stages/tile, proven
// swizzle (phys 16B slot = g ^ ((row>>1)&3) on source + ds_read).
// Ledger: per-tile vmem window = 2 A-stages + 4 B-loads = 6; end-of-tile
// vmcnt(12) spans windows t,t-1 -> all older ops (incl. slot-(t+1) A-stages
// from window t-2) retired; asm "memory" fences stop cross-window motion;
// B-register correctness via compiler-inserted waits. Tail: clamped dead
// re-stages. Epilogue: R9/R14-validated packed full-line stores (the B
// permutation n = b+4r+j is baked into the pack).
// ---------------------------------------------------------------------------
#define STAGE16(SRC, DST)                                                     \
  __builtin_amdgcn_global_load_lds(                                           \
      (const __attribute__((address_space(1))) void*)(SRC),                   \
      (__attribute__((address_space(3))) void*)(DST), 16, 0, 0)

#define RD(p) (*(const i32x4*)(p))

#define TILE(SLOT, KSTG, TN, DO_NEXT)                                         \
  {                                                                           \
    const char* bufA_ = &lds[SLOT][0];                                        \
    char* nA_ = &lds[((SLOT) + 3) & 3][0];                                    \
    i32x4 a1_[4];                                                             \
    _Pragma("unroll") for (int i_ = 0; i_ < 4; ++i_)                          \
        a1_[i_] = RD(bufA_ + aoff[4 + i_]);                                   \
    STAGE16(asrc0 + (size_t)(KSTG) * 64, nA_ + o0_);                          \
    STAGE16(asrc1 + (size_t)(KSTG) * 64, nA_ + o1_);                          \
    __builtin_amdgcn_s_setprio(1);                                            \
    _Pragma("unroll") for (int i_ = 0; i_ < 4; ++i_)                          \
        _Pragma("unroll") for (int j_ = 0; j_ < 4; ++j_)                      \
            acc[i_][j_] = __builtin_amdgcn_mfma_i32_16x16x64_i8(              \
                a0[i_], b0[j_], acc[i_][j_], 0, 0, 0);                        \
    __builtin_amdgcn_s_setprio(0);                                            \
    i32x4 ta_[4], bn_[4];                                                     \
    if (DO_NEXT) {                                                            \
      const char* xA_ = &lds[((SLOT) + 1) & 3][0];                            \
      _Pragma("unroll") for (int i_ = 0; i_ < 4; ++i_)                        \
          ta_[i_] = RD(xA_ + aoff[i_]);                                       \
      _Pragma("unroll") for (int j_ = 0; j_ < 4; ++j_)                        \
          bn_[j_] = RD(bptr[j_] + (size_t)(TN) * 1024);                       \
    }                                                                         \
    __builtin_amdgcn_s_setprio(1);                                            \
    _Pragma("unroll") for (int i_ = 0; i_ < 4; ++i_)                          \
        _Pragma("unroll") for (int j_ = 0; j_ < 4; ++j_)                      \
            acc[4 + i_][j_] = __builtin_amdgcn_mfma_i32_16x16x64_i8(          \
                a1_[i_], b0[j_], acc[4 + i_][j_], 0, 0, 0);                   \
    __builtin_amdgcn_s_setprio(0);                                            \
    asm volatile("s_waitcnt vmcnt(12)" ::: "memory");                         \
    __builtin_amdgcn_s_barrier();                                             \
    if (DO_NEXT) {                                                            \
      _Pragma("unroll") for (int i_ = 0; i_ < 4; ++i_) a0[i_] = ta_[i_];      \
      _Pragma("unroll") for (int j_ = 0; j_ < 4; ++j_) b0[j_] = bn_[j_];      \
    }                                                                         \
  }

template <int WRITE_Q>
__global__ __launch_bounds__(512, 2) void gemm_kernel(
    const char* __restrict__ qa, const char* __restrict__ wbp,
    const int* __restrict__ corr, const float* __restrict__ swp,
    const float* __restrict__ bias, const float* __restrict__ sp,
    const int* __restrict__ zpp, char* __restrict__ outq, float* __restrict__ outf) {
  __shared__ __align__(16) char lds[4][16384];  // 64 KB: A-only 4-slot ring
  const int tid = threadIdx.x;
  const int lane = tid & 63;
  const int w = tid >> 6;
  const int wr = w >> 2;   // 0..1 (M)
  const int wc = w & 3;    // 0..3 (N)
  const int bid = blockIdx.x;
  const int bm = bid & 31;  // M/256 = 32, fastest: neighbors share B panel
  const int bn = bid >> 5;  // N/256 = 16
  const char* abase = qa + (size_t)bm * 256 * K_DIM;

  // --- A staging constants (inverse-swizzled global sources, R14-proven) ---
  const int o0_ = tid * 16;
  const int o1_ = 8192 + tid * 16;
  const int r0_ = o0_ >> 6, r1_ = o1_ >> 6;
  const int g0_ = ((o0_ >> 4) & 3) ^ ((r0_ >> 1) & 3);
  const int g1_ = ((o1_ >> 4) & 3) ^ ((r1_ >> 1) & 3);
  const char* asrc0 = abase + (size_t)r0_ * K_DIM + g0_ * 16;
  const char* asrc1 = abase + (size_t)r1_ * K_DIM + g1_ * 16;

  // --- B direct: per-wave fragment base pointers into packed W ---
  // frag j covers n-group (bn*256 + wc*64) + {4r+j}; F = group/16 + j.
  const int Fbase = (bn * 256 + wc * 64) >> 4;
  const char* bptr[4];
#pragma unroll
  for (int j = 0; j < 4; ++j)
    bptr[j] = wbp + (size_t)(Fbase + j) * 64 * 1024 + lane * 16;

  // --- per-thread A ds_read byte offsets (swizzled) ---
  const int rr = lane & 15;
  const int g = lane >> 4;
  int aoff[8];
#pragma unroll
  for (int i = 0; i < 8; ++i) {
    const int row = wr * 128 + i * 16 + rr;
    aoff[i] = (row << 6) + ((g ^ ((row >> 1) & 3)) << 4);
  }

  i32x4 acc[8][4] = {};

  // --- prologue: stage A slots 0,1,2 (6 ops) + load B tile 0 (4 ops) ---
  STAGE16(asrc0, &lds[0][o0_]); STAGE16(asrc1, &lds[0][o1_]);
  STAGE16(asrc0 + 64, &lds[1][o0_]); STAGE16(asrc1 + 64, &lds[1][o1_]);
  STAGE16(asrc0 + 128, &lds[2][o0_]); STAGE16(asrc1 + 128, &lds[2][o1_]);
  i32x4 a0[4], b0[4];
#pragma unroll
  for (int j = 0; j < 4; ++j) b0[j] = RD(bptr[j]);
  asm volatile("s_waitcnt vmcnt(8)" ::: "memory");  // slot 0 A-stages retired
  __builtin_amdgcn_s_barrier();
#pragma unroll
  for (int i = 0; i < 4; ++i) a0[i] = RD(&lds[0][0] + aoff[i]);

  // --- main loop: t = 0..59 (slots cycle 0..3); stage t+3, load B t+1 ---
  for (int tb = 0; tb < (KTILES - 4) / 4; ++tb) {
    const int t0 = tb * 4;
#pragma unroll
    for (int u = 0; u < 4; ++u) {
      TILE(u, t0 + u + 3, t0 + u + 1, 1);
    }
  }
  // --- peeled tail: t = 60..63; A-stage clamps to 63 (dead re-stages) ---
  TILE(0, KTILES - 1, 61, 1);
  TILE(1, KTILES - 1, 62, 1);
  TILE(2, KTILES - 1, 63, 1);
  TILE(3, KTILES - 1, 63, 0);
  asm volatile("s_waitcnt vmcnt(0)" ::: "memory");  // drain before exit

  // --- epilogue (R9/R14-validated): frag j, lane c -> n = nb4 + j ---
  const float s = sp[0];
  const float zpf = (float)zpp[0];
  const int m0 = bm * 256 + wr * 128 + (lane >> 4) * 4;
  const int nb4 = bn * 256 + wc * 64 + ((lane & 15) << 2);
  const int4 cr4 = *(const int4*)(corr + nb4);
  const float4 sw4 = *(const float4*)(swp + nb4);
  const float4 bb4 = *(const float4*)(bias + nb4);
  const float fs0 = s * sw4.x, fs1 = s * sw4.y, fs2 = s * sw4.z, fs3 = s * sw4.w;
#pragma unroll
  for (int i = 0; i < 8; ++i) {
#pragma unroll
    for (int q = 0; q < 4; ++q) {
      const int m = m0 + i * 16 + q;
      const float v0 = fs0 * (float)(acc[i][0][q] + cr4.x) + bb4.x;
      const float v1 = fs1 * (float)(acc[i][1][q] + cr4.y) + bb4.y;
      const float v2 = fs2 * (float)(acc[i][2][q] + cr4.z) + bb4.z;
      const float v3 = fs3 * (float)(acc[i][3][q] + cr4.w) + bb4.w;
      if (WRITE_Q) {
        const int b0i = (int)fminf(fmaxf(rintf(v0 / s) + zpf, 0.f), 255.f) - 128;
        const int b1i = (int)fminf(fmaxf(rintf(v1 / s) + zpf, 0.f), 255.f) - 128;
        const int b2i = (int)fminf(fmaxf(rintf(v2 / s) + zpf, 0.f), 255.f) - 128;
        const int b3i = (int)fminf(fmaxf(rintf(v3 / s) + zpf, 0.f), 255.f) - 128;
        const uint32_t pk = (uint32_t)(b0i & 255) | ((uint32_t)(b1i & 255) << 8) |
                            ((uint32_t)(b2i & 255) << 16) | ((uint32_t)b3i << 24);
        *(uint32_t*)(outq + (size_t)m * N_DIM + nb4) = pk;
      } else {
        float4 o4;
        o4.x = v0; o4.y = v1; o4.z = v2; o4.w = v3;
        *(float4*)(outf + (size_t)m * N_DIM + nb4) = o4;
      }
    }
  }
}

// ---------------------------------------------------------------------------
extern "C" void kernel_launch(void* const* d_in, const int* in_sizes, int n_in,
                              void* d_out, int out_size, void* d_ws, size_t ws_size,
                              hipStream_t stream) {
  const float* x = (const float*)d_in[0];
  const int* wq = (const int*)d_in[1];
  const float* bias = (const float*)d_in[2];
  const float* s_in = (const float*)d_in[3];
  const int* zp_in = (const int*)d_in[4];
  const float* s_w = (const float*)d_in[5];
  float* out = (float*)d_out;

  const size_t WP_BYTES = (size_t)N_DIM * K_DIM;  // 16 MB packed int8 W
  const size_t Q_BYTES = (size_t)M_DIM * K_DIM;   // 32 MB int8 activations
  char* ws = (char*)d_ws;
  char* wp = ws;
  char* q1 = ws + WP_BYTES;
  char* q2 = q1 + Q_BYTES;
  int* corr = (int*)(q2 + Q_BYTES);
  const size_t NEEDED = WP_BYTES + 2 * Q_BYTES + (size_t)N_DIM * sizeof(int);
  if (ws_size < NEEDED) return;

  pack_w_kernel<<<N_DIM, 256, 0, stream>>>(wq, wp, corr, zp_in);
  quant_in_kernel<<<(M_DIM * K_DIM / 4) / 256, 256, 0, stream>>>(x, q1, s_in, zp_in);

  dim3 grid((M_DIM / 256) * (N_DIM / 256));  // 512 blocks
  dim3 blk(512);
  gemm_kernel<1><<<grid, blk, 0, stream>>>(q1, wp, corr, s_w, bias, s_in, zp_in, q2, nullptr);
  gemm_kernel<1><<<grid, blk, 0, stream>>>(q2, wp, corr, s_w, bias, s_in, zp_in, q1, nullptr);
  gemm_kernel<0><<<grid, blk, 0, stream>>>(q1, wp, corr, s_w, bias, s_in, zp_in, nullptr, out);
}